// Round 11
// baseline (197.086 us; speedup 1.0000x reference)
//
#include <hip/hip_runtime.h>
#include <stdint.h>
#include <type_traits>

typedef unsigned short u16;
using short8  = __attribute__((ext_vector_type(8))) short;
using ushort8 = __attribute__((ext_vector_type(8))) unsigned short;
using floatx4 = __attribute__((ext_vector_type(4))) float;

#define IC(n) (std::integral_constant<int, (n)>())

__device__ __forceinline__ u16 f2bf(float f) {
    unsigned u = __float_as_uint(f);
    u += 0x7fff + ((u >> 16) & 1);   // round-to-nearest-even
    return (u16)(u >> 16);
}
__device__ __forceinline__ float bf2f(u16 h) {
    return __uint_as_float(((unsigned)h) << 16);
}

// async global->LDS, 16B per lane (global_load_lds_dwordx4)
__device__ __forceinline__ void gload_lds16(const void* g, void* l) {
    auto gp = reinterpret_cast<const __attribute__((address_space(1))) unsigned int*>(
        reinterpret_cast<uintptr_t>(g));
    auto lp = reinterpret_cast<__attribute__((address_space(3))) unsigned int*>(
        reinterpret_cast<uintptr_t>(l));
    __builtin_amdgcn_global_load_lds(gp, lp, 16, 0, 0);
}

// 1) convert x f32 -> bf16 ----------------------------------------------------
__global__ __launch_bounds__(256) void cvt_f32_bf16_kernel(
        const float* __restrict__ in, u16* __restrict__ out) {
    long i = ((long)blockIdx.x * 256 + threadIdx.x) * 4;
    float4 v = *(const float4*)(in + i);
    ushort4 o;
    o.x = f2bf(v.x); o.y = f2bf(v.y); o.z = f2bf(v.z); o.w = f2bf(v.w);
    *(ushort4*)(out + i) = o;
}

// 2) W [1024][1024] f32 -> Wt bf16 [e][d] (transpose+convert), 3 weights ------
__global__ __launch_bounds__(256) void wt_kernel(
        const float* __restrict__ W0, const float* __restrict__ W1, const float* __restrict__ W2,
        u16* __restrict__ O0, u16* __restrict__ O1, u16* __restrict__ O2) {
    const float* W = blockIdx.z == 0 ? W0 : blockIdx.z == 1 ? W1 : W2;
    u16* O = blockIdx.z == 0 ? O0 : blockIdx.z == 1 ? O1 : O2;
    __shared__ float t[32][33];
    const int cx = threadIdx.x & 31, ry = threadIdx.x >> 5;
    const int d0 = blockIdx.x * 32, e0 = blockIdx.y * 32;
#pragma unroll
    for (int i = 0; i < 4; i++) t[ry + i * 8][cx] = W[(long)(d0 + ry + i * 8) * 1024 + e0 + cx];
    __syncthreads();
#pragma unroll
    for (int i = 0; i < 4; i++) O[(long)(e0 + ry + i * 8) * 1024 + d0 + cx] = f2bf(t[cx][ry + i * 8]);
}

// 3) V bf16 [4][2048][1024] -> Vt bf16 [4][1024][2048], vectorized ------------
__global__ __launch_bounds__(256) void vt_kernel(
        const u16* __restrict__ V, u16* __restrict__ Vt) {
    const int b = blockIdx.z;
    const u16* v = V + (long)b * 2048 * 1024;
    u16* o = Vt + (long)b * 1024 * 2048;
    __shared__ u16 t[64][68];
    const int c4 = (threadIdx.x & 15) * 4, r = threadIdx.x >> 4;
    const int e0 = blockIdx.x * 64, t0 = blockIdx.y * 64;
#pragma unroll
    for (int i = 0; i < 4; i++)
        *(ushort4*)&t[r + i * 16][c4] =
            *(const ushort4*)(v + (long)(t0 + r + i * 16) * 1024 + e0 + c4);
    __syncthreads();
#pragma unroll
    for (int i = 0; i < 4; i++) {
        const int e = r + i * 16;
        ushort4 d;
        d.x = t[c4 + 0][e]; d.y = t[c4 + 1][e]; d.z = t[c4 + 2][e]; d.w = t[c4 + 3][e];
        *(ushort4*)(o + (long)(e0 + e) * 2048 + t0 + c4) = d;
    }
}

// 4) 128x128 4-phase GEMM, 16x16x32 core, 2 blocks/CU -------------------------
// Same as round 10; FIX: LB base is dbuf*DB + 8192 (B tile offset), not +16384.
// MODE 0: QKV fused (bias, 3 split bf16 outputs, row stride 1024)
// MODE 1: scores (*scale, bf16 out, batched)
// MODE 2: PV (f32 out, batched)
template <int MODE>
__global__ __launch_bounds__(512) void gemm8_kernel(
        const u16* __restrict__ A, const u16* __restrict__ Bt,
        void* __restrict__ out0, void* __restrict__ out1, void* __restrict__ out2,
        const float* __restrict__ b0, const float* __restrict__ b1, const float* __restrict__ b2,
        int K, int N, long sAb, long sBb, long sCb, float scale)
{
    extern __shared__ u16 lds[];
    constexpr int DB = 16384;        // u16 per dbuf (A 8192 + B 8192)
    const int tid = threadIdx.x, lane = tid & 63, wid = tid >> 6;
    const int wm = wid >> 1, wn = wid & 1;      // 4m x 2n waves, wave tile 32x64
    const int l15 = lane & 15, hib = (lane >> 4) * 16;

    // XCD-aware bijective swizzle (all grids have nwg % 8 == 0)
    const int nbx = gridDim.x;
    const int nwg = nbx * gridDim.y;
    int lin = blockIdx.y * nbx + blockIdx.x;
    lin = (lin & 7) * (nwg >> 3) + (lin >> 3);
    const long m0 = (long)(lin / nbx) * 128;
    const long n0 = (long)(lin % nbx) * 128;

    const u16* Ab = A + (long)blockIdx.z * sAb;
    const u16* Bb = Bt + (long)blockIdx.z * sBb;
    const long ldk = K;
    const int NT = K >> 6;          // K-tiles of 64

    // ---- staging: one tile side = 128x64 bf16 = 16KB = 2 gloads/thread ------
    auto stA = [&](int dbuf, int kt) {
#pragma unroll
        for (int i = 0; i < 2; ++i) {
            const int R  = i * 64 + (tid >> 3);
            const int cb = (tid & 7) * 16;
            const int scb = cb ^ ((R & 7) << 4);        // inverse swizzle on SOURCE
            const u16* src = Ab + (m0 + R) * ldk + (long)kt * 64 + (scb >> 1);
            u16* dst = lds + dbuf * DB + i * 4096 + tid * 8;
            gload_lds16(src, dst);
        }
    };
    auto stB = [&](int dbuf, int kt) {
#pragma unroll
        for (int i = 0; i < 2; ++i) {
            const int R  = i * 64 + (tid >> 3);
            const int cb = (tid & 7) * 16;
            const int scb = cb ^ ((R & 7) << 4);
            const u16* src = Bb + (n0 + R) * ldk + (long)kt * 64 + (scb >> 1);
            u16* dst = lds + dbuf * DB + 8192 + i * 4096 + tid * 8;
            gload_lds16(src, dst);
        }
    };

    floatx4 acc[2][4] = {};          // 2 m-frags x 4 n-frags
    short8 a[2][2], b[4][2];         // [frag][ks]

    auto LA = [&](int dbuf) {
        const char* reg = (const char*)(lds + dbuf * DB);
#pragma unroll
        for (int fm = 0; fm < 2; ++fm)
#pragma unroll
            for (int ks = 0; ks < 2; ++ks) {
                const int r = wm * 32 + fm * 16 + l15;
                const int cb = ks * 64 + hib;
                a[fm][ks] = *(const short8*)(reg + r * 128 + (cb ^ ((r & 7) << 4)));
            }
    };
    auto LB = [&](int dbuf) {
        const char* reg = (const char*)(lds + dbuf * DB + 8192);   // FIX: B at +8192
#pragma unroll
        for (int fn = 0; fn < 4; ++fn)
#pragma unroll
            for (int ks = 0; ks < 2; ++ks) {
                const int r = wn * 64 + fn * 16 + l15;
                const int cb = ks * 64 + hib;
                b[fn][ks] = *(const short8*)(reg + r * 128 + (cb ^ ((r & 7) << 4)));
            }
    };
    auto MM = [&](auto FMc) {        // one m-frag x all 4 n-frags x 2 ks = 8 MFMA
        constexpr int FM = decltype(FMc)::value;
        __builtin_amdgcn_s_setprio(1);
#pragma unroll
        for (int ks = 0; ks < 2; ++ks)
#pragma unroll
            for (int fn = 0; fn < 4; ++fn)
                acc[FM][fn] = __builtin_amdgcn_mfma_f32_16x16x32_bf16(
                    a[FM][ks], b[fn][ks], acc[FM][fn], 0, 0, 0);
        __builtin_amdgcn_s_setprio(0);
    };

#define BAR() __builtin_amdgcn_s_barrier()

    // ---- prologue: kt0 {A,B} -> dbuf0, kt1 {A} -> dbuf1; keep kt1-A in flight
    stA(0, 0); stB(0, 0);
    stA(1, 1);
    asm volatile("s_waitcnt vmcnt(2)");
    BAR();

    // ---- main loop: one iteration = 2 K-tiles = 4 phases ---------------------
    auto pair = [&](auto LASTC, int kt0) {
        constexpr bool L = decltype(LASTC)::value;
        // Pa0 (kt0, dbuf0): finish staging kt1 (B); read + first m-frag
        stB(1, kt0 + 1);
        LA(0); LB(0);
        BAR(); MM(IC(0)); BAR();
        // Pb0: stage kt2-A into dbuf0 (its reads drained); gate kt1 ready
        if (!L) stA(0, kt0 + 2);
        BAR(); MM(IC(1));
        if (L) asm volatile("s_waitcnt vmcnt(0)");
        else   asm volatile("s_waitcnt vmcnt(2)");
        BAR();
        // Pa1 (kt0+1, dbuf1): stage kt2-B; read + first m-frag
        if (!L) stB(0, kt0 + 2);
        LA(1); LB(1);
        BAR(); MM(IC(0)); BAR();
        // Pb1: stage kt3-A into dbuf1; gate kt2 ready
        if (!L) stA(1, kt0 + 3);
        BAR(); MM(IC(1));
        if (L) asm volatile("s_waitcnt vmcnt(0)");
        else   asm volatile("s_waitcnt vmcnt(2)");
        BAR();
    };

    const int NITER = NT >> 1;
    int it = 0;
    for (; it < NITER - 1; ++it) pair(std::false_type{}, 2 * it);
    pair(std::true_type{}, 2 * it);

#undef BAR

    // ---- epilogue: swizzled LDS bounce -> coalesced global stores ------------
    // 16x16 C/D layout: col=lane&15, row=(lane>>4)*4+j (HW-verified)
    const int cr = (lane >> 4) * 4, cc = l15;
    char* ldsB = (char*)lds;
    __syncthreads();   // staging LDS fully dead
    if (MODE == 2) {
#pragma unroll
        for (int fn = 0; fn < 4; ++fn) {
            const int col = wn * 64 + fn * 16 + cc;
#pragma unroll
            for (int fm = 0; fm < 2; ++fm) {
                const int row = wm * 32 + fm * 16 + cr;
#pragma unroll
                for (int j = 0; j < 4; ++j)
                    *(float*)(ldsB + ((((row + j) * 128 + col) * 4) ^ (((row + j) & 7) << 4))) =
                        acc[fm][fn][j];
            }
        }
        __syncthreads();
        float* O = (float*)out0 + (long)blockIdx.z * sCb;
#pragma unroll
        for (int i = 0; i < 8; ++i) {              // 128*128 f32 / 4 / 512
            const int g4 = tid + i * 512;
            const int row = g4 >> 5;                // 32 float4 per row
            const int c4  = g4 & 31;
            float4 v = *(const float4*)(ldsB + ((g4 * 16) ^ ((row & 7) << 4)));
            *(float4*)(O + (m0 + row) * (long)N + n0 + c4 * 4) = v;
        }
    } else {
        const int sel = (MODE == 0) ? (int)(n0 >> 10) : 0;
        const float* bias = (MODE == 0) ? (sel == 0 ? b0 : sel == 1 ? b1 : b2) : nullptr;
        const long nc0 = n0 & 1023;
#pragma unroll
        for (int fn = 0; fn < 4; ++fn) {
            const int col = wn * 64 + fn * 16 + cc;
            const float bvv = (MODE == 0) ? bias[nc0 + col] : 0.f;
#pragma unroll
            for (int fm = 0; fm < 2; ++fm) {
                const int row = wm * 32 + fm * 16 + cr;
#pragma unroll
                for (int j = 0; j < 4; ++j) {
                    float v = acc[fm][fn][j];
                    if (MODE == 1) v *= scale;
                    v += bvv;
                    *(u16*)(ldsB + ((((row + j) * 128 + col) * 2) ^ (((row + j) & 7) << 4))) = f2bf(v);
                }
            }
        }
        __syncthreads();
#pragma unroll
        for (int i = 0; i < 4; ++i) {              // 128*128 bf16 / 8 / 512
            const int g8 = tid + i * 512;
            const int row = g8 >> 4;                // 16 ushort8 per row
            const int c8  = g8 & 15;
            ushort8 v = *(const ushort8*)(ldsB + ((g8 * 16) ^ ((row & 7) << 4)));
            if (MODE == 0) {
                u16* O = (u16*)(sel == 0 ? out0 : sel == 1 ? out1 : out2);
                *(ushort8*)(O + (m0 + row) * 1024 + nc0 + c8 * 8) = v;
            } else {
                u16* O = (u16*)out0 + (long)blockIdx.z * sCb;
                *(ushort8*)(O + (m0 + row) * (long)N + n0 + c8 * 8) = v;
            }
        }
    }
}

// 5) in-place row softmax over 2048 bf16 --------------------------------------
__global__ __launch_bounds__(256) void softmax_kernel(u16* __restrict__ S) {
    u16* p = S + (long)blockIdx.x * 2048;
    const int tid = threadIdx.x;
    union { int4 q; u16 u[8]; } in;
    in.q = *(const int4*)(p + tid * 8);
    float v[8];
#pragma unroll
    for (int i = 0; i < 8; i++) v[i] = bf2f(in.u[i]);
    float mx = v[0];
#pragma unroll
    for (int i = 1; i < 8; i++) mx = fmaxf(mx, v[i]);
#pragma unroll
    for (int off = 32; off; off >>= 1) mx = fmaxf(mx, __shfl_xor(mx, off));
    __shared__ float red[8];
    if ((tid & 63) == 0) red[tid >> 6] = mx;
    __syncthreads();
    mx = fmaxf(fmaxf(red[0], red[1]), fmaxf(red[2], red[3]));
    float s = 0.f;
#pragma unroll
    for (int i = 0; i < 8; i++) { v[i] = __expf(v[i] - mx); s += v[i]; }
#pragma unroll
    for (int off = 32; off; off >>= 1) s += __shfl_xor(s, off);
    if ((tid & 63) == 0) red[4 + (tid >> 6)] = s;
    __syncthreads();
    s = red[4] + red[5] + red[6] + red[7];
    const float inv = 1.f / s;
    union { int4 q; u16 u[8]; } out;
#pragma unroll
    for (int i = 0; i < 8; i++) out.u[i] = f2bf(v[i] * inv);
    *(int4*)(p + tid * 8) = out.q;
}

// -----------------------------------------------------------------------------
extern "C" void kernel_launch(void* const* d_in, const int* in_sizes, int n_in,
                              void* d_out, int out_size, void* d_ws, size_t ws_size,
                              hipStream_t stream) {
    const float* x  = (const float*)d_in[0];
    const float* Wq = (const float*)d_in[1];
    const float* bq = (const float*)d_in[2];
    const float* Wk = (const float*)d_in[3];
    const float* bk = (const float*)d_in[4];
    const float* Wv = (const float*)d_in[5];
    const float* bv = (const float*)d_in[6];
    float* out = (float*)d_out;

    char* ws = (char*)d_ws;
    const long MB = 1L << 20;
    u16* xb = (u16*)(ws);            // 16 MB  x bf16 [8192][1024]
    u16* wt = (u16*)(ws + 16 * MB);  // 6 MB   W{q,k,v}^T bf16 [3072][1024] stacked
    u16* Q  = (u16*)(ws + 22 * MB);  // 16 MB  [4][2048][1024]
    u16* Kb = (u16*)(ws + 38 * MB);  // 16 MB
    u16* Vb = (u16*)(ws + 54 * MB);  // 16 MB
    u16* Vt = (u16*)(ws + 70 * MB);  // 16 MB  [4][1024][2048]
    u16* Sc = (u16*)(ws + 86 * MB);  // 32 MB  scores/attn [4][2048][2048]

    (void)hipFuncSetAttribute((const void*)gemm8_kernel<0>, hipFuncAttributeMaxDynamicSharedMemorySize, 65536);
    (void)hipFuncSetAttribute((const void*)gemm8_kernel<1>, hipFuncAttributeMaxDynamicSharedMemorySize, 65536);
    (void)hipFuncSetAttribute((const void*)gemm8_kernel<2>, hipFuncAttributeMaxDynamicSharedMemorySize, 65536);

    // x -> bf16
    cvt_f32_bf16_kernel<<<8192, 256, 0, stream>>>(x, xb);
    // W -> Wt bf16 (transposed, stacked)
    wt_kernel<<<dim3(32, 32, 3), 256, 0, stream>>>(Wq, Wk, Wv, wt, wt + 1024 * 1024, wt + 2 * 1024 * 1024);
    // fused QKV: [8192][1024] @ [3072][1024]^T + bias — 1536 blocks, 2/CU -> 3 generations
    gemm8_kernel<0><<<dim3(24, 64, 1), 512, 65536, stream>>>(
        xb, wt, Q, Kb, Vb, bq, bk, bv, 1024, 3072, 0, 0, 0, 1.f);
    // V -> V^T per batch (vectorized 64x64 tiles)
    vt_kernel<<<dim3(16, 32, 4), 256, 0, stream>>>(Vb, Vt);
    // scores = (Q @ K^T) / 32, bf16, batched — 1024 blocks -> 2 generations
    gemm8_kernel<1><<<dim3(16, 16, 4), 512, 65536, stream>>>(
        Q, Kb, Sc, nullptr, nullptr, nullptr, nullptr, nullptr,
        1024, 2048, 2048L * 1024, 2048L * 1024, 2048L * 2048, 0.03125f);
    // softmax rows, in place
    softmax_kernel<<<8192, 256, 0, stream>>>(Sc);
    // out = attn @ V, f32 out, batched — 512 blocks -> 1 generation
    gemm8_kernel<2><<<dim3(8, 16, 4), 512, 65536, stream>>>(
        Sc, Vt, out, nullptr, nullptr, nullptr, nullptr, nullptr,
        2048, 1024, 2048L * 2048, 1024L * 2048, 2048L * 1024, 1.f);
}

// Round 12
// 173.907 us; speedup vs baseline: 1.1333x; 1.1333x over previous
//
#include <hip/hip_runtime.h>
#include <stdint.h>
#include <type_traits>

typedef unsigned short u16;
using short8  = __attribute__((ext_vector_type(8))) short;
using ushort8 = __attribute__((ext_vector_type(8))) unsigned short;
using floatx4 = __attribute__((ext_vector_type(4))) float;

#define IC(n) (std::integral_constant<int, (n)>())

__device__ __forceinline__ u16 f2bf(float f) {
    unsigned u = __float_as_uint(f);
    u += 0x7fff + ((u >> 16) & 1);   // round-to-nearest-even
    return (u16)(u >> 16);
}
__device__ __forceinline__ float bf2f(u16 h) {
    return __uint_as_float(((unsigned)h) << 16);
}

// async global->LDS, 16B per lane (global_load_lds_dwordx4)
__device__ __forceinline__ void gload_lds16(const void* g, void* l) {
    auto gp = reinterpret_cast<const __attribute__((address_space(1))) unsigned int*>(
        reinterpret_cast<uintptr_t>(g));
    auto lp = reinterpret_cast<__attribute__((address_space(3))) unsigned int*>(
        reinterpret_cast<uintptr_t>(l));
    __builtin_amdgcn_global_load_lds(gp, lp, 16, 0, 0);
}

// 1) convert x f32 -> bf16 ----------------------------------------------------
__global__ __launch_bounds__(256) void cvt_f32_bf16_kernel(
        const float* __restrict__ in, u16* __restrict__ out) {
    long i = ((long)blockIdx.x * 256 + threadIdx.x) * 4;
    float4 v = *(const float4*)(in + i);
    ushort4 o;
    o.x = f2bf(v.x); o.y = f2bf(v.y); o.z = f2bf(v.z); o.w = f2bf(v.w);
    *(ushort4*)(out + i) = o;
}

// 2) W [1024][1024] f32 -> Wt bf16 [e][d] (transpose+convert), 3 weights ------
__global__ __launch_bounds__(256) void wt_kernel(
        const float* __restrict__ W0, const float* __restrict__ W1, const float* __restrict__ W2,
        u16* __restrict__ O0, u16* __restrict__ O1, u16* __restrict__ O2) {
    const float* W = blockIdx.z == 0 ? W0 : blockIdx.z == 1 ? W1 : W2;
    u16* O = blockIdx.z == 0 ? O0 : blockIdx.z == 1 ? O1 : O2;
    __shared__ float t[32][33];
    const int cx = threadIdx.x & 31, ry = threadIdx.x >> 5;
    const int d0 = blockIdx.x * 32, e0 = blockIdx.y * 32;
#pragma unroll
    for (int i = 0; i < 4; i++) t[ry + i * 8][cx] = W[(long)(d0 + ry + i * 8) * 1024 + e0 + cx];
    __syncthreads();
#pragma unroll
    for (int i = 0; i < 4; i++) O[(long)(e0 + ry + i * 8) * 1024 + d0 + cx] = f2bf(t[cx][ry + i * 8]);
}

// 3) 256xBNT 4-phase GEMM (r8-verified): C = A[M][K] @ Bt[N][K]^T --------------
// K-loop schedule, staging, swizzle, gates: byte-identical to round 8.
// Epilogue: coalesced via swizzled LDS bounce. NEW: MODE 0 V-blocks (sel==2)
// bounce TRANSPOSED -> write Vt[4][1024][2048] directly (kills vt kernel).
// MODE 0: QKV fused (bias; Q,K row-major; V transposed into Vt)
// MODE 1: scores (*scale, bf16 out, batched)
// MODE 2: PV (f32 out, batched)
template <int MODE, int BNT>
__global__ __launch_bounds__(512) void gemm8_kernel(
        const u16* __restrict__ A, const u16* __restrict__ Bt,
        void* __restrict__ out0, void* __restrict__ out1, void* __restrict__ out2,
        const float* __restrict__ b0, const float* __restrict__ b1, const float* __restrict__ b2,
        int K, int N, long sAb, long sBb, long sCb, float scale)
{
    extern __shared__ u16 lds[];
    constexpr int DB   = (BNT == 256) ? 32768 : 24576;  // u16 per dbuf
    constexpr int FNH  = (BNT == 256) ? 2 : 1;          // B frags per NH
    constexpr int WCOL = (BNT == 256) ? 64 : 32;        // wave col width
    const int tid = threadIdx.x, lane = tid & 63, wid = tid >> 6;
    const int wm = wid >> 2, wn = wid & 3;
    const int l15 = lane & 15, hib = (lane >> 4) * 16;

    // XCD-aware bijective swizzle (all grids have nwg % 8 == 0)
    const int nbx = gridDim.x;
    const int nwg = nbx * gridDim.y;
    int lin = blockIdx.y * nbx + blockIdx.x;
    lin = (lin & 7) * (nwg >> 3) + (lin >> 3);
    const long m0 = (long)(lin / nbx) * 256;
    const long n0 = (long)(lin % nbx) * BNT;

    const u16* Ab = A + (long)blockIdx.z * sAb;
    const u16* Bb = Bt + (long)blockIdx.z * sBb;
    const long ldk = K;
    const int NT = K >> 6;          // K-tiles of 64

    // ---- staging ------------------------------------------------------------
    auto stA = [&](int dbuf, int S, int kt) {
#pragma unroll
        for (int i = 0; i < 2; ++i) {
            const int rl = tid >> 3;
            const int R  = S * 64 + rl;
            const int cb = (tid & 7) * 16;
            const int scb = cb ^ ((R & 7) << 4);        // inverse swizzle on SOURCE
            const u16* src = Ab + (m0 + i * 128 + R) * ldk + (long)kt * 64 + (scb >> 1);
            u16* dst = lds + dbuf * DB + i * 8192 + S * 4096 + wid * 512;
            gload_lds16(src, dst);
        }
    };
    auto stB = [&](int dbuf, int NHs, int kt) {   // BNT==256 only
#pragma unroll
        for (int i = 0; i < 2; ++i) {
            const int c = i * 2 + (wid >> 2);
            const int h = c >> 1, rb = (c & 1) * 64;
            const int w = (wid & 3) * 64 + lane;
            const int r32 = w >> 3;
            const int R = rb + NHs * 32 + r32;
            const int cb = (w & 7) * 16;
            const int scb = cb ^ ((R & 7) << 4);
            const u16* src = Bb + (n0 + h * 128 + R) * ldk + (long)kt * 64 + (scb >> 1);
            u16* dst = lds + dbuf * DB + 16384 + h * 8192 + (rb + NHs * 32) * 64 + (wid & 3) * 512;
            gload_lds16(src, dst);
        }
    };
    auto stB128 = [&](int dbuf, int kt) {          // BNT==128 only: one 128x64 unit
#pragma unroll
        for (int i = 0; i < 2; ++i) {
            const int R = i * 64 + (tid >> 3);
            const int cb = (tid & 7) * 16;
            const int scb = cb ^ ((R & 7) << 4);
            const u16* src = Bb + (n0 + R) * ldk + (long)kt * 64 + (scb >> 1);
            u16* dst = lds + dbuf * DB + 16384 + i * 4096 + tid * 8;
            gload_lds16(src, dst);
        }
    };

    floatx4 acc[8][2 * FNH] = {};
    short8 afr[4][2], bfr[FNH][2];

    auto LA = [&](int dbuf, auto MHc) {
        constexpr int MH = decltype(MHc)::value;
        const char* reg = (const char*)(lds + dbuf * DB + wm * 8192);
#pragma unroll
        for (int fm = 0; fm < 4; ++fm)
#pragma unroll
            for (int ks = 0; ks < 2; ++ks) {
                const int r = MH * 64 + fm * 16 + l15;
                const int cb = ks * 64 + hib;
                afr[fm][ks] = *(const short8*)(reg + r * 128 + (cb ^ ((r & 7) << 4)));
            }
    };
    auto LB = [&](int dbuf, auto NHc) {
        constexpr int NH = decltype(NHc)::value;
        if constexpr (BNT == 256) {
            const char* reg = (const char*)(lds + dbuf * DB + 16384 + (wn >> 1) * 8192);
#pragma unroll
            for (int fn = 0; fn < 2; ++fn)
#pragma unroll
                for (int ks = 0; ks < 2; ++ks) {
                    const int r = (wn & 1) * 64 + NH * 32 + fn * 16 + l15;
                    const int cb = ks * 64 + hib;
                    bfr[fn][ks] = *(const short8*)(reg + r * 128 + (cb ^ ((r & 7) << 4)));
                }
        } else {
            const char* reg = (const char*)(lds + dbuf * DB + 16384);
#pragma unroll
            for (int ks = 0; ks < 2; ++ks) {
                const int r = wn * 32 + decltype(NHc)::value * 16 + l15;
                const int cb = ks * 64 + hib;
                bfr[0][ks] = *(const short8*)(reg + r * 128 + (cb ^ ((r & 7) << 4)));
            }
        }
    };
    auto MM = [&](auto MHc, auto NHc) {
        constexpr int MH = decltype(MHc)::value;
        constexpr int NH = decltype(NHc)::value;
        __builtin_amdgcn_s_setprio(1);
#pragma unroll
        for (int ks = 0; ks < 2; ++ks)        // ks outer: dependent pairs 8 apart
#pragma unroll
            for (int fm = 0; fm < 4; ++fm)
#pragma unroll
                for (int fn = 0; fn < FNH; ++fn)
                    acc[MH * 4 + fm][NH * FNH + fn] = __builtin_amdgcn_mfma_f32_16x16x32_bf16(
                        afr[fm][ks], bfr[fn][ks], acc[MH * 4 + fm][NH * FNH + fn], 0, 0, 0);
        __builtin_amdgcn_s_setprio(0);
    };

#define BAR() __builtin_amdgcn_s_barrier()

    // ---- prologue ------------------------------------------------------------
    if constexpr (BNT == 256) {
        stA(0, 0, 0); stA(0, 1, 0); stB(0, 0, 0); stB(0, 1, 0);
        stA(1, 0, 1); stB(1, 1, 1);
        asm volatile("s_waitcnt vmcnt(4)");
    } else {
        stA(0, 0, 0); stA(0, 1, 0); stB128(0, 0);
        stA(1, 0, 1);
        asm volatile("s_waitcnt vmcnt(2)");
    }
    BAR();

    // ---- main loop: one iteration = 2 K-tiles = 4 merged phases --------------
    auto pair = [&](auto LASTC, int kt0) {
        constexpr bool L = decltype(LASTC)::value;
        if constexpr (BNT == 256) {
            stA(1, 1, kt0 + 1); stB(1, 0, kt0 + 1);
            LA(0, IC(0)); LB(0, IC(0));
            BAR();
            MM(IC(0), IC(0));
            LB(0, IC(1));
            MM(IC(0), IC(1));
            LA(0, IC(1));
            BAR();
            if (!L) { stA(0, 0, kt0 + 2); stB(0, 1, kt0 + 2); }
            BAR();
            MM(IC(1), IC(1));
            LB(0, IC(0));
            MM(IC(1), IC(0));
            if (L) asm volatile("s_waitcnt vmcnt(0)");
            else   asm volatile("s_waitcnt vmcnt(4)");
            BAR();
            if (!L) { stA(0, 1, kt0 + 2); stB(0, 0, kt0 + 2); }
            LA(1, IC(0)); LB(1, IC(0));
            BAR();
            MM(IC(0), IC(0));
            LB(1, IC(1));
            MM(IC(0), IC(1));
            LA(1, IC(1));
            BAR();
            if (!L) { stA(1, 0, kt0 + 3); stB(1, 1, kt0 + 3); }
            BAR();
            MM(IC(1), IC(1));
            LB(1, IC(0));
            MM(IC(1), IC(0));
            if (L) asm volatile("s_waitcnt vmcnt(0)");
            else   asm volatile("s_waitcnt vmcnt(4)");
            BAR();
        } else {
            stA(1, 1, kt0 + 1); stB128(1, kt0 + 1);
            LA(0, IC(0)); LB(0, IC(0));
            BAR();
            MM(IC(0), IC(0));
            LB(0, IC(1));
            MM(IC(0), IC(1));
            LA(0, IC(1));
            BAR();
            if (!L) stA(0, 0, kt0 + 2);
            BAR();
            MM(IC(1), IC(1));
            LB(0, IC(0));
            MM(IC(1), IC(0));
            if (L) asm volatile("s_waitcnt vmcnt(0)");
            else   asm volatile("s_waitcnt vmcnt(2)");
            BAR();
            if (!L) { stA(0, 1, kt0 + 2); stB128(0, kt0 + 2); }
            LA(1, IC(0)); LB(1, IC(0));
            BAR();
            MM(IC(0), IC(0));
            LB(1, IC(1));
            MM(IC(0), IC(1));
            LA(1, IC(1));
            BAR();
            if (!L) stA(1, 0, kt0 + 3);
            BAR();
            MM(IC(1), IC(1));
            LB(1, IC(0));
            MM(IC(1), IC(0));
            if (L) asm volatile("s_waitcnt vmcnt(0)");
            else   asm volatile("s_waitcnt vmcnt(2)");
            BAR();
        }
    };

    const int NITER = NT >> 1;
    int it = 0;
    for (; it < NITER - 1; ++it) pair(std::false_type{}, 2 * it);
    pair(std::true_type{}, 2 * it);

#undef BAR

    // ---- epilogue: swizzled LDS bounce -> coalesced global stores -----------
    // C/D frag layout: col=lane&15, row=(lane>>4)*4+j (HW-verified).
    const int cr = (lane >> 4) * 4, cc = l15;
    char* ldsB = (char*)lds;
    const int sel = (MODE == 0) ? (int)(n0 >> 10) : 0;
    __syncthreads();   // staging LDS fully dead
    if (MODE == 2) {
#pragma unroll
        for (int an = 0; an < 2 * FNH; ++an) {
            const int col = wn * WCOL + an * 16 + cc;
#pragma unroll
            for (int am = 0; am < 8; ++am) {
                const int row = wm * 128 + am * 16 + cr;
#pragma unroll
                for (int j = 0; j < 4; ++j)
                    *(float*)(ldsB + ((((row + j) * BNT + col) * 4) ^ (((row + j) & 7) << 4))) =
                        acc[am][an][j];
            }
        }
        __syncthreads();
        constexpr int NIT = 256 * BNT / 4 / 512;       // float4 copies per thread
        float* O = (float*)out0 + (long)blockIdx.z * sCb;
#pragma unroll
        for (int i = 0; i < NIT; ++i) {
            const int g4 = tid + i * 512;
            const int row = g4 >> 5;                    // BNT=128: 32 float4 per row
            const int c4  = g4 & 31;
            float4 v = *(const float4*)(ldsB + ((g4 * 16) ^ ((row & 7) << 4)));
            *(float4*)(O + (m0 + row) * (long)N + n0 + c4 * 4) = v;
        }
    } else if (MODE == 0 && sel == 2) {
        // V: TRANSPOSED bounce -> Vt[4][1024][2048]. LDS layout [e:BNT][t:256]
        // u16, byte (e*512 + t*2) ^ ((e&7)<<4)  (bijective within each e-row;
        // 16 lanes x distinct e -> 8 slots x 2-way = free).
        const long nc0 = n0 & 1023;
        const long b = m0 >> 11, tb = m0 & 2047;   // 2048 % 256 == 0: no crossing
#pragma unroll
        for (int an = 0; an < 2 * FNH; ++an) {
            const int e = wn * WCOL + an * 16 + cc;
            const float bvv = b2[nc0 + e];
#pragma unroll
            for (int am = 0; am < 8; ++am) {
                const int t = wm * 128 + am * 16 + cr;
                ushort4 w;
                w.x = f2bf(acc[am][an][0] + bvv);
                w.y = f2bf(acc[am][an][1] + bvv);
                w.z = f2bf(acc[am][an][2] + bvv);
                w.w = f2bf(acc[am][an][3] + bvv);   // j contiguous in t -> 8B store
                *(ushort4*)(ldsB + (((e * 256 + t) * 2) ^ ((e & 7) << 4))) = w;
            }
        }
        __syncthreads();
        constexpr int NIT = 256 * BNT / 8 / 512;       // ushort8 copies per thread
        u16* O = (u16*)out2 + b * 1024L * 2048 + nc0 * 2048 + tb;
#pragma unroll
        for (int i = 0; i < NIT; ++i) {
            const int g8 = tid + i * 512;
            const int e  = g8 >> 5;                     // 32 ushort8 per e-row
            const int c8 = g8 & 31;
            ushort8 v = *(const ushort8*)(ldsB + ((g8 * 16) ^ ((e & 7) << 4)));
            *(ushort8*)(O + (long)e * 2048 + c8 * 8) = v;
        }
    } else {
        const float* bias = (MODE == 0) ? (sel == 0 ? b0 : b1) : nullptr;
        const long nc0 = n0 & 1023;
#pragma unroll
        for (int an = 0; an < 2 * FNH; ++an) {
            const int col = wn * WCOL + an * 16 + cc;
            const float bvv = (MODE == 0) ? bias[nc0 + col] : 0.f;
#pragma unroll
            for (int am = 0; am < 8; ++am) {
                const int row = wm * 128 + am * 16 + cr;
#pragma unroll
                for (int j = 0; j < 4; ++j) {
                    float v = acc[am][an][j];
                    if (MODE == 1) v *= scale;
                    v += bvv;
                    *(u16*)(ldsB + ((((row + j) * BNT + col) * 2) ^ (((row + j) & 7) << 4))) = f2bf(v);
                }
            }
        }
        __syncthreads();
        constexpr int NIT = 256 * BNT / 8 / 512;       // ushort8 copies per thread
        constexpr int RSH = (BNT == 256) ? 5 : 4;      // 16B chunks per row
#pragma unroll
        for (int i = 0; i < NIT; ++i) {
            const int g8 = tid + i * 512;
            const int row = g8 >> RSH;
            const int c8  = g8 & ((BNT >> 3) - 1);
            ushort8 v = *(const ushort8*)(ldsB + ((g8 * 16) ^ ((row & 7) << 4)));
            if (MODE == 0) {
                u16* O = (u16*)(sel == 0 ? out0 : out1);
                *(ushort8*)(O + (m0 + row) * 1024 + nc0 + c8 * 8) = v;
            } else {
                u16* O = (u16*)out0 + (long)blockIdx.z * sCb;
                *(ushort8*)(O + (m0 + row) * (long)N + n0 + c8 * 8) = v;
            }
        }
    }
}

// 4) in-place row softmax over 2048 bf16 --------------------------------------
__global__ __launch_bounds__(256) void softmax_kernel(u16* __restrict__ S) {
    u16* p = S + (long)blockIdx.x * 2048;
    const int tid = threadIdx.x;
    union { int4 q; u16 u[8]; } in;
    in.q = *(const int4*)(p + tid * 8);
    float v[8];
#pragma unroll
    for (int i = 0; i < 8; i++) v[i] = bf2f(in.u[i]);
    float mx = v[0];
#pragma unroll
    for (int i = 1; i < 8; i++) mx = fmaxf(mx, v[i]);
#pragma unroll
    for (int off = 32; off; off >>= 1) mx = fmaxf(mx, __shfl_xor(mx, off));
    __shared__ float red[8];
    if ((tid & 63) == 0) red[tid >> 6] = mx;
    __syncthreads();
    mx = fmaxf(fmaxf(red[0], red[1]), fmaxf(red[2], red[3]));
    float s = 0.f;
#pragma unroll
    for (int i = 0; i < 8; i++) { v[i] = __expf(v[i] - mx); s += v[i]; }
#pragma unroll
    for (int off = 32; off; off >>= 1) s += __shfl_xor(s, off);
    if ((tid & 63) == 0) red[4 + (tid >> 6)] = s;
    __syncthreads();
    s = red[4] + red[5] + red[6] + red[7];
    const float inv = 1.f / s;
    union { int4 q; u16 u[8]; } out;
#pragma unroll
    for (int i = 0; i < 8; i++) out.u[i] = f2bf(v[i] * inv);
    *(int4*)(p + tid * 8) = out.q;
}

// -----------------------------------------------------------------------------
extern "C" void kernel_launch(void* const* d_in, const int* in_sizes, int n_in,
                              void* d_out, int out_size, void* d_ws, size_t ws_size,
                              hipStream_t stream) {
    const float* x  = (const float*)d_in[0];
    const float* Wq = (const float*)d_in[1];
    const float* bq = (const float*)d_in[2];
    const float* Wk = (const float*)d_in[3];
    const float* bk = (const float*)d_in[4];
    const float* Wv = (const float*)d_in[5];
    const float* bv = (const float*)d_in[6];
    float* out = (float*)d_out;

    char* ws = (char*)d_ws;
    const long MB = 1L << 20;
    u16* xb = (u16*)(ws);            // 16 MB  x bf16 [8192][1024]
    u16* wt = (u16*)(ws + 16 * MB);  // 6 MB   W{q,k,v}^T bf16 [3072][1024] stacked
    u16* Q  = (u16*)(ws + 22 * MB);  // 16 MB  [4][2048][1024]
    u16* Kb = (u16*)(ws + 38 * MB);  // 16 MB
    u16* Vt = (u16*)(ws + 54 * MB);  // 16 MB  [4][1024][2048]  (written directly by QKV)
    u16* Sc = (u16*)(ws + 70 * MB);  // 32 MB  scores/attn [4][2048][2048]

    (void)hipFuncSetAttribute((const void*)gemm8_kernel<0, 128>, hipFuncAttributeMaxDynamicSharedMemorySize, 98304);
    (void)hipFuncSetAttribute((const void*)gemm8_kernel<1, 256>, hipFuncAttributeMaxDynamicSharedMemorySize, 131072);
    (void)hipFuncSetAttribute((const void*)gemm8_kernel<2, 128>, hipFuncAttributeMaxDynamicSharedMemorySize, 131072);

    // x -> bf16
    cvt_f32_bf16_kernel<<<8192, 256, 0, stream>>>(x, xb);
    // W -> Wt bf16 (transposed, stacked)
    wt_kernel<<<dim3(32, 32, 3), 256, 0, stream>>>(Wq, Wk, Wv, wt, wt + 1024 * 1024, wt + 2 * 1024 * 1024);
    // fused QKV: [8192][1024] @ [3072][1024]^T + bias — 768 blocks = 3 exact generations.
    // Q,K row-major; V written TRANSPOSED into Vt by the epilogue bounce.
    gemm8_kernel<0, 128><<<dim3(24, 32, 1), 512, 98304, stream>>>(
        xb, wt, Q, Kb, Vt, bq, bk, bv, 1024, 3072, 0, 0, 0, 1.f);
    // scores = (Q @ K^T) / 32, bf16, batched — 256 blocks = 1 generation
    gemm8_kernel<1, 256><<<dim3(8, 8, 4), 512, 131072, stream>>>(
        Q, Kb, Sc, nullptr, nullptr, nullptr, nullptr, nullptr,
        1024, 2048, 2048L * 1024, 2048L * 1024, 2048L * 2048, 0.03125f);
    // softmax rows, in place
    softmax_kernel<<<8192, 256, 0, stream>>>(Sc);
    // out = attn @ V, f32 out, batched — 256 blocks = 1 generation
    gemm8_kernel<2, 128><<<dim3(8, 8, 4), 512, 131072, stream>>>(
        Sc, Vt, out, nullptr, nullptr, nullptr, nullptr, nullptr,
        2048, 1024, 2048L * 2048, 1024L * 2048, 2048L * 1024, 1.f);
}

// Round 13
// 167.003 us; speedup vs baseline: 1.1801x; 1.0413x over previous
//
#include <hip/hip_runtime.h>
#include <stdint.h>
#include <type_traits>

typedef unsigned short u16;
using short8  = __attribute__((ext_vector_type(8))) short;
using ushort8 = __attribute__((ext_vector_type(8))) unsigned short;
using floatx4 = __attribute__((ext_vector_type(4))) float;

#define IC(n) (std::integral_constant<int, (n)>())

__device__ __forceinline__ u16 f2bf(float f) {
    unsigned u = __float_as_uint(f);
    u += 0x7fff + ((u >> 16) & 1);   // round-to-nearest-even
    return (u16)(u >> 16);
}
__device__ __forceinline__ float bf2f(u16 h) {
    return __uint_as_float(((unsigned)h) << 16);
}

// async global->LDS, 16B per lane (global_load_lds_dwordx4)
__device__ __forceinline__ void gload_lds16(const void* g, void* l) {
    auto gp = reinterpret_cast<const __attribute__((address_space(1))) unsigned int*>(
        reinterpret_cast<uintptr_t>(g));
    auto lp = reinterpret_cast<__attribute__((address_space(3))) unsigned int*>(
        reinterpret_cast<uintptr_t>(l));
    __builtin_amdgcn_global_load_lds(gp, lp, 16, 0, 0);
}

// 1) convert x f32 -> bf16 ----------------------------------------------------
__global__ __launch_bounds__(256) void cvt_f32_bf16_kernel(
        const float* __restrict__ in, u16* __restrict__ out) {
    long i = ((long)blockIdx.x * 256 + threadIdx.x) * 4;
    float4 v = *(const float4*)(in + i);
    ushort4 o;
    o.x = f2bf(v.x); o.y = f2bf(v.y); o.z = f2bf(v.z); o.w = f2bf(v.w);
    *(ushort4*)(out + i) = o;
}

// 2) W [1024][1024] f32 -> Wt bf16 [e][d] (transpose+convert), 3 weights ------
__global__ __launch_bounds__(256) void wt_kernel(
        const float* __restrict__ W0, const float* __restrict__ W1, const float* __restrict__ W2,
        u16* __restrict__ O0, u16* __restrict__ O1, u16* __restrict__ O2) {
    const float* W = blockIdx.z == 0 ? W0 : blockIdx.z == 1 ? W1 : W2;
    u16* O = blockIdx.z == 0 ? O0 : blockIdx.z == 1 ? O1 : O2;
    __shared__ float t[32][33];
    const int cx = threadIdx.x & 31, ry = threadIdx.x >> 5;
    const int d0 = blockIdx.x * 32, e0 = blockIdx.y * 32;
#pragma unroll
    for (int i = 0; i < 4; i++) t[ry + i * 8][cx] = W[(long)(d0 + ry + i * 8) * 1024 + e0 + cx];
    __syncthreads();
#pragma unroll
    for (int i = 0; i < 4; i++) O[(long)(e0 + ry + i * 8) * 1024 + d0 + cx] = f2bf(t[cx][ry + i * 8]);
}

// 3) 256xBNT 4-phase GEMM: C = A[M][K] @ Bt[N][K]^T ---------------------------
// Sync skeleton (stage slots / vmcnt gates / barriers / prologue): byte-identical
// to round 12 (verified). BNT=128 wave grid reshaped 2mx4n -> 4mx2n (wave tile
// 64x64): LDS read redundancy A x4->x2, B x2->x4 => 176->128 KB/kt, and both
// B n-halves held in regs (no Pb re-read). Register-neutral (acc 64, bfr +16,
// afr -16). BNT=256 (scores) path untouched.
// MODE 0: QKV fused (bias; Q,K row-major; V transposed into Vt)
// MODE 1: scores (*scale, bf16 out, batched)
// MODE 2: PV (f32 out, batched)
template <int MODE, int BNT>
__global__ __launch_bounds__(512) void gemm8_kernel(
        const u16* __restrict__ A, const u16* __restrict__ Bt,
        void* __restrict__ out0, void* __restrict__ out1, void* __restrict__ out2,
        const float* __restrict__ b0, const float* __restrict__ b1, const float* __restrict__ b2,
        int K, int N, long sAb, long sBb, long sCb, float scale)
{
    extern __shared__ u16 lds[];
    constexpr int DB = (BNT == 256) ? 32768 : 24576;  // u16 per dbuf
    constexpr int RF = (BNT == 256) ? 8 : 4;          // row frags per wave
    constexpr int AF = (BNT == 256) ? 4 : 2;          // A frags held
    constexpr int BF = (BNT == 256) ? 2 : 4;          // B frags held
    const int tid = threadIdx.x, lane = tid & 63, wid = tid >> 6;
    const int wm = (BNT == 256) ? (wid >> 2) : (wid >> 1);
    const int wn = (BNT == 256) ? (wid & 3) : (wid & 1);
    const int l15 = lane & 15, hib = (lane >> 4) * 16;

    // XCD-aware bijective swizzle (all grids have nwg % 8 == 0)
    const int nbx = gridDim.x;
    const int nwg = nbx * gridDim.y;
    int lin = blockIdx.y * nbx + blockIdx.x;
    lin = (lin & 7) * (nwg >> 3) + (lin >> 3);
    const long m0 = (long)(lin / nbx) * 256;
    const long n0 = (long)(lin % nbx) * BNT;

    const u16* Ab = A + (long)blockIdx.z * sAb;
    const u16* Bb = Bt + (long)blockIdx.z * sBb;
    const long ldk = K;
    const int NT = K >> 6;          // K-tiles of 64

    // ---- staging ------------------------------------------------------------
    auto stA = [&](int dbuf, int S, int kt) {
#pragma unroll
        for (int i = 0; i < 2; ++i) {
            const int rl = tid >> 3;
            const int R  = S * 64 + rl;
            const int cb = (tid & 7) * 16;
            const int scb = cb ^ ((R & 7) << 4);        // inverse swizzle on SOURCE
            const u16* src = Ab + (m0 + i * 128 + R) * ldk + (long)kt * 64 + (scb >> 1);
            u16* dst = lds + dbuf * DB + i * 8192 + S * 4096 + wid * 512;
            gload_lds16(src, dst);
        }
    };
    auto stB = [&](int dbuf, int NHs, int kt) {   // BNT==256 only
#pragma unroll
        for (int i = 0; i < 2; ++i) {
            const int c = i * 2 + (wid >> 2);
            const int h = c >> 1, rb = (c & 1) * 64;
            const int w = (wid & 3) * 64 + lane;
            const int r32 = w >> 3;
            const int R = rb + NHs * 32 + r32;
            const int cb = (w & 7) * 16;
            const int scb = cb ^ ((R & 7) << 4);
            const u16* src = Bb + (n0 + h * 128 + R) * ldk + (long)kt * 64 + (scb >> 1);
            u16* dst = lds + dbuf * DB + 16384 + h * 8192 + (rb + NHs * 32) * 64 + (wid & 3) * 512;
            gload_lds16(src, dst);
        }
    };
    auto stB128 = [&](int dbuf, int kt) {          // BNT==128 only: one 128x64 unit
#pragma unroll
        for (int i = 0; i < 2; ++i) {
            const int R = i * 64 + (tid >> 3);
            const int cb = (tid & 7) * 16;
            const int scb = cb ^ ((R & 7) << 4);
            const u16* src = Bb + (n0 + R) * ldk + (long)kt * 64 + (scb >> 1);
            u16* dst = lds + dbuf * DB + 16384 + i * 4096 + tid * 8;
            gload_lds16(src, dst);
        }
    };

    floatx4 acc[RF][4] = {};
    short8 afr[AF][2], bfr[BF][2];

    auto LA = [&](int dbuf, auto MHc) {
        constexpr int MH = decltype(MHc)::value;
        if constexpr (BNT == 256) {
            const char* reg = (const char*)(lds + dbuf * DB + wm * 8192);
#pragma unroll
            for (int fm = 0; fm < 4; ++fm)
#pragma unroll
                for (int ks = 0; ks < 2; ++ks) {
                    const int r = MH * 64 + fm * 16 + l15;
                    const int cb = ks * 64 + hib;
                    afr[fm][ks] = *(const short8*)(reg + r * 128 + (cb ^ ((r & 7) << 4)));
                }
        } else {
            const char* reg = (const char*)(lds + dbuf * DB);
#pragma unroll
            for (int fm = 0; fm < 2; ++fm)
#pragma unroll
                for (int ks = 0; ks < 2; ++ks) {
                    const int r = wm * 64 + MH * 32 + fm * 16 + l15;
                    const int cb = ks * 64 + hib;
                    afr[fm][ks] = *(const short8*)(reg + r * 128 + (cb ^ ((r & 7) << 4)));
                }
        }
    };
    auto LB = [&](int dbuf, auto NHc) {
        constexpr int NH = decltype(NHc)::value;
        if constexpr (BNT == 256) {
            const char* reg = (const char*)(lds + dbuf * DB + 16384 + (wn >> 1) * 8192);
#pragma unroll
            for (int fn = 0; fn < 2; ++fn)
#pragma unroll
                for (int ks = 0; ks < 2; ++ks) {
                    const int r = (wn & 1) * 64 + NH * 32 + fn * 16 + l15;
                    const int cb = ks * 64 + hib;
                    bfr[fn][ks] = *(const short8*)(reg + r * 128 + (cb ^ ((r & 7) << 4)));
                }
        } else {
            const char* reg = (const char*)(lds + dbuf * DB + 16384);
#pragma unroll
            for (int fn = 0; fn < 2; ++fn)
#pragma unroll
                for (int ks = 0; ks < 2; ++ks) {
                    const int r = wn * 64 + NH * 32 + fn * 16 + l15;
                    const int cb = ks * 64 + hib;
                    bfr[NH * 2 + fn][ks] = *(const short8*)(reg + r * 128 + (cb ^ ((r & 7) << 4)));
                }
        }
    };
    auto MM = [&](auto MHc, auto NHc) {
        constexpr int MH = decltype(MHc)::value;
        constexpr int NH = decltype(NHc)::value;
        __builtin_amdgcn_s_setprio(1);
        if constexpr (BNT == 256) {
#pragma unroll
            for (int ks = 0; ks < 2; ++ks)
#pragma unroll
                for (int fm = 0; fm < 4; ++fm)
#pragma unroll
                    for (int fn = 0; fn < 2; ++fn)
                        acc[MH * 4 + fm][NH * 2 + fn] = __builtin_amdgcn_mfma_f32_16x16x32_bf16(
                            afr[fm][ks], bfr[fn][ks], acc[MH * 4 + fm][NH * 2 + fn], 0, 0, 0);
        } else {
#pragma unroll
            for (int ks = 0; ks < 2; ++ks)
#pragma unroll
                for (int fm = 0; fm < 2; ++fm)
#pragma unroll
                    for (int fn = 0; fn < 2; ++fn)
                        acc[MH * 2 + fm][NH * 2 + fn] = __builtin_amdgcn_mfma_f32_16x16x32_bf16(
                            afr[fm][ks], bfr[NH * 2 + fn][ks], acc[MH * 2 + fm][NH * 2 + fn], 0, 0, 0);
        }
        __builtin_amdgcn_s_setprio(0);
    };

#define BAR() __builtin_amdgcn_s_barrier()

    // ---- prologue (identical to r12) -----------------------------------------
    if constexpr (BNT == 256) {
        stA(0, 0, 0); stA(0, 1, 0); stB(0, 0, 0); stB(0, 1, 0);
        stA(1, 0, 1); stB(1, 1, 1);
        asm volatile("s_waitcnt vmcnt(4)");
    } else {
        stA(0, 0, 0); stA(0, 1, 0); stB128(0, 0);
        stA(1, 0, 1);
        asm volatile("s_waitcnt vmcnt(2)");
    }
    BAR();

    // ---- main loop: one iteration = 2 K-tiles = 4 merged phases --------------
    auto pair = [&](auto LASTC, int kt0) {
        constexpr bool L = decltype(LASTC)::value;
        if constexpr (BNT == 256) {
            stA(1, 1, kt0 + 1); stB(1, 0, kt0 + 1);
            LA(0, IC(0)); LB(0, IC(0));
            BAR();
            MM(IC(0), IC(0));
            LB(0, IC(1));
            MM(IC(0), IC(1));
            LA(0, IC(1));
            BAR();
            if (!L) { stA(0, 0, kt0 + 2); stB(0, 1, kt0 + 2); }
            BAR();
            MM(IC(1), IC(1));
            LB(0, IC(0));
            MM(IC(1), IC(0));
            if (L) asm volatile("s_waitcnt vmcnt(0)");
            else   asm volatile("s_waitcnt vmcnt(4)");
            BAR();
            if (!L) { stA(0, 1, kt0 + 2); stB(0, 0, kt0 + 2); }
            LA(1, IC(0)); LB(1, IC(0));
            BAR();
            MM(IC(0), IC(0));
            LB(1, IC(1));
            MM(IC(0), IC(1));
            LA(1, IC(1));
            BAR();
            if (!L) { stA(1, 0, kt0 + 3); stB(1, 1, kt0 + 3); }
            BAR();
            MM(IC(1), IC(1));
            LB(1, IC(0));
            MM(IC(1), IC(0));
            if (L) asm volatile("s_waitcnt vmcnt(0)");
            else   asm volatile("s_waitcnt vmcnt(4)");
            BAR();
        } else {
            // Pa0 (kt0, dbuf0): stage slots as r12; read A(mh0) + both B halves
            stA(1, 1, kt0 + 1); stB128(1, kt0 + 1);
            LA(0, IC(0)); LB(0, IC(0)); LB(0, IC(1));
            BAR();
            MM(IC(0), IC(0));
            MM(IC(0), IC(1));
            LA(0, IC(1));                 // A(mh1), overwrites afr after last use
            BAR();
            // Pb0
            if (!L) stA(0, 0, kt0 + 2);
            BAR();
            MM(IC(1), IC(1));
            MM(IC(1), IC(0));
            if (L) asm volatile("s_waitcnt vmcnt(0)");
            else   asm volatile("s_waitcnt vmcnt(2)");
            BAR();
            // Pa1 (kt0+1, dbuf1)
            if (!L) { stA(0, 1, kt0 + 2); stB128(0, kt0 + 2); }
            LA(1, IC(0)); LB(1, IC(0)); LB(1, IC(1));
            BAR();
            MM(IC(0), IC(0));
            MM(IC(0), IC(1));
            LA(1, IC(1));
            BAR();
            // Pb1
            if (!L) stA(1, 0, kt0 + 3);
            BAR();
            MM(IC(1), IC(1));
            MM(IC(1), IC(0));
            if (L) asm volatile("s_waitcnt vmcnt(0)");
            else   asm volatile("s_waitcnt vmcnt(2)");
            BAR();
        }
    };

    const int NITER = NT >> 1;
    int it = 0;
    for (; it < NITER - 1; ++it) pair(std::false_type{}, 2 * it);
    pair(std::true_type{}, 2 * it);

#undef BAR

    // ---- epilogue: swizzled LDS bounce -> coalesced global stores -----------
    // C/D frag layout: col=lane&15, row=(lane>>4)*4+j (HW-verified).
    // Wave tile: rows [wm*RF*16, +RF*16), cols [wn*64, +64) for both BNT paths.
    const int cr = (lane >> 4) * 4, cc = l15;
    const int rowbase = wm * (RF * 16), colbase = wn * 64;
    char* ldsB = (char*)lds;
    const int sel = (MODE == 0) ? (int)(n0 >> 10) : 0;
    __syncthreads();   // staging LDS fully dead
    if (MODE == 2) {
#pragma unroll
        for (int j = 0; j < 4; ++j) {
            const int col = colbase + j * 16 + cc;
#pragma unroll
            for (int i = 0; i < RF; ++i) {
                const int row = rowbase + i * 16 + cr;
#pragma unroll
                for (int jj = 0; jj < 4; ++jj)
                    *(float*)(ldsB + ((((row + jj) * BNT + col) * 4) ^ (((row + jj) & 7) << 4))) =
                        acc[i][j][jj];
            }
        }
        __syncthreads();
        constexpr int NIT = 256 * BNT / 4 / 512;       // float4 copies per thread
        float* O = (float*)out0 + (long)blockIdx.z * sCb;
#pragma unroll
        for (int i = 0; i < NIT; ++i) {
            const int g4 = tid + i * 512;
            const int row = g4 >> 5;                    // BNT=128: 32 float4 per row
            const int c4  = g4 & 31;
            float4 v = *(const float4*)(ldsB + ((g4 * 16) ^ ((row & 7) << 4)));
            *(float4*)(O + (m0 + row) * (long)N + n0 + c4 * 4) = v;
        }
    } else if (MODE == 0 && sel == 2) {
        // V: TRANSPOSED bounce -> Vt[4][1024][2048]. LDS layout [e:BNT][t:256]
        const long nc0 = n0 & 1023;
        const long b = m0 >> 11, tb = m0 & 2047;   // 2048 % 256 == 0: no crossing
#pragma unroll
        for (int j = 0; j < 4; ++j) {
            const int e = colbase + j * 16 + cc;
            const float bvv = b2[nc0 + e];
#pragma unroll
            for (int i = 0; i < RF; ++i) {
                const int t = rowbase + i * 16 + cr;
                ushort4 w;
                w.x = f2bf(acc[i][j][0] + bvv);
                w.y = f2bf(acc[i][j][1] + bvv);
                w.z = f2bf(acc[i][j][2] + bvv);
                w.w = f2bf(acc[i][j][3] + bvv);   // j contiguous in t -> 8B store
                *(ushort4*)(ldsB + (((e * 256 + t) * 2) ^ ((e & 7) << 4))) = w;
            }
        }
        __syncthreads();
        constexpr int NIT = 256 * BNT / 8 / 512;       // ushort8 copies per thread
        u16* O = (u16*)out2 + b * 1024L * 2048 + nc0 * 2048 + tb;
#pragma unroll
        for (int i = 0; i < NIT; ++i) {
            const int g8 = tid + i * 512;
            const int e  = g8 >> 5;                     // 32 ushort8 per e-row
            const int c8 = g8 & 31;
            ushort8 v = *(const ushort8*)(ldsB + ((g8 * 16) ^ ((e & 7) << 4)));
            *(ushort8*)(O + (long)e * 2048 + c8 * 8) = v;
        }
    } else {
        const float* bias = (MODE == 0) ? (sel == 0 ? b0 : b1) : nullptr;
        const long nc0 = n0 & 1023;
#pragma unroll
        for (int j = 0; j < 4; ++j) {
            const int col = colbase + j * 16 + cc;
            const float bvv = (MODE == 0) ? bias[nc0 + col] : 0.f;
#pragma unroll
            for (int i = 0; i < RF; ++i) {
                const int row = rowbase + i * 16 + cr;
#pragma unroll
                for (int jj = 0; jj < 4; ++jj) {
                    float v = acc[i][j][jj];
                    if (MODE == 1) v *= scale;
                    v += bvv;
                    *(u16*)(ldsB + ((((row + jj) * BNT + col) * 2) ^ (((row + jj) & 7) << 4))) = f2bf(v);
                }
            }
        }
        __syncthreads();
        constexpr int NIT = 256 * BNT / 8 / 512;       // ushort8 copies per thread
        constexpr int RSH = (BNT == 256) ? 5 : 4;      // 16B chunks per row
#pragma unroll
        for (int i = 0; i < NIT; ++i) {
            const int g8 = tid + i * 512;
            const int row = g8 >> RSH;
            const int c8  = g8 & ((BNT >> 3) - 1);
            ushort8 v = *(const ushort8*)(ldsB + ((g8 * 16) ^ ((row & 7) << 4)));
            if (MODE == 0) {
                u16* O = (u16*)(sel == 0 ? out0 : out1);
                *(ushort8*)(O + (m0 + row) * 1024 + nc0 + c8 * 8) = v;
            } else {
                u16* O = (u16*)out0 + (long)blockIdx.z * sCb;
                *(ushort8*)(O + (m0 + row) * (long)N + n0 + c8 * 8) = v;
            }
        }
    }
}

// 4) in-place row softmax over 2048 bf16 --------------------------------------
__global__ __launch_bounds__(256) void softmax_kernel(u16* __restrict__ S) {
    u16* p = S + (long)blockIdx.x * 2048;
    const int tid = threadIdx.x;
    union { int4 q; u16 u[8]; } in;
    in.q = *(const int4*)(p + tid * 8);
    float v[8];
#pragma unroll
    for (int i = 0; i < 8; i++) v[i] = bf2f(in.u[i]);
    float mx = v[0];
#pragma unroll
    for (int i = 1; i < 8; i++) mx = fmaxf(mx, v[i]);
#pragma unroll
    for (int off = 32; off; off >>= 1) mx = fmaxf(mx, __shfl_xor(mx, off));
    __shared__ float red[8];
    if ((tid & 63) == 0) red[tid >> 6] = mx;
    __syncthreads();
    mx = fmaxf(fmaxf(red[0], red[1]), fmaxf(red[2], red[3]));
    float s = 0.f;
#pragma unroll
    for (int i = 0; i < 8; i++) { v[i] = __expf(v[i] - mx); s += v[i]; }
#pragma unroll
    for (int off = 32; off; off >>= 1) s += __shfl_xor(s, off);
    if ((tid & 63) == 0) red[4 + (tid >> 6)] = s;
    __syncthreads();
    s = red[4] + red[5] + red[6] + red[7];
    const float inv = 1.f / s;
    union { int4 q; u16 u[8]; } out;
#pragma unroll
    for (int i = 0; i < 8; i++) out.u[i] = f2bf(v[i] * inv);
    *(int4*)(p + tid * 8) = out.q;
}

// -----------------------------------------------------------------------------
extern "C" void kernel_launch(void* const* d_in, const int* in_sizes, int n_in,
                              void* d_out, int out_size, void* d_ws, size_t ws_size,
                              hipStream_t stream) {
    const float* x  = (const float*)d_in[0];
    const float* Wq = (const float*)d_in[1];
    const float* bq = (const float*)d_in[2];
    const float* Wk = (const float*)d_in[3];
    const float* bk = (const float*)d_in[4];
    const float* Wv = (const float*)d_in[5];
    const float* bv = (const float*)d_in[6];
    float* out = (float*)d_out;

    char* ws = (char*)d_ws;
    const long MB = 1L << 20;
    u16* xb = (u16*)(ws);            // 16 MB  x bf16 [8192][1024]
    u16* wt = (u16*)(ws + 16 * MB);  // 6 MB   W{q,k,v}^T bf16 [3072][1024] stacked
    u16* Q  = (u16*)(ws + 22 * MB);  // 16 MB  [4][2048][1024]
    u16* Kb = (u16*)(ws + 38 * MB);  // 16 MB
    u16* Vt = (u16*)(ws + 54 * MB);  // 16 MB  [4][1024][2048]  (written directly by QKV)
    u16* Sc = (u16*)(ws + 70 * MB);  // 32 MB  scores/attn [4][2048][2048]

    (void)hipFuncSetAttribute((const void*)gemm8_kernel<0, 128>, hipFuncAttributeMaxDynamicSharedMemorySize, 98304);
    (void)hipFuncSetAttribute((const void*)gemm8_kernel<1, 256>, hipFuncAttributeMaxDynamicSharedMemorySize, 131072);
    (void)hipFuncSetAttribute((const void*)gemm8_kernel<2, 128>, hipFuncAttributeMaxDynamicSharedMemorySize, 131072);

    // x -> bf16
    cvt_f32_bf16_kernel<<<8192, 256, 0, stream>>>(x, xb);
    // W -> Wt bf16 (transposed, stacked)
    wt_kernel<<<dim3(32, 32, 3), 256, 0, stream>>>(Wq, Wk, Wv, wt, wt + 1024 * 1024, wt + 2 * 1024 * 1024);
    // fused QKV: [8192][1024] @ [3072][1024]^T + bias — 768 blocks = 3 exact generations.
    // Q,K row-major; V written TRANSPOSED into Vt by the epilogue bounce.
    gemm8_kernel<0, 128><<<dim3(24, 32, 1), 512, 98304, stream>>>(
        xb, wt, Q, Kb, Vt, bq, bk, bv, 1024, 3072, 0, 0, 0, 1.f);
    // scores = (Q @ K^T) / 32, bf16, batched — 256 blocks = 1 generation
    gemm8_kernel<1, 256><<<dim3(8, 8, 4), 512, 131072, stream>>>(
        Q, Kb, Sc, nullptr, nullptr, nullptr, nullptr, nullptr,
        1024, 2048, 2048L * 1024, 2048L * 1024, 2048L * 2048, 0.03125f);
    // softmax rows, in place
    softmax_kernel<<<8192, 256, 0, stream>>>(Sc);
    // out = attn @ V, f32 out, batched — 256 blocks = 1 generation
    gemm8_kernel<2, 128><<<dim3(8, 8, 4), 512, 131072, stream>>>(
        Sc, Vt, out, nullptr, nullptr, nullptr, nullptr, nullptr,
        2048, 1024, 2048L * 2048, 1024L * 2048, 2048L * 1024, 1.f);
}